// Round 1
// baseline (390.727 us; speedup 1.0000x reference)
//
#include <hip/hip_runtime.h>
#include <hip/hip_bf16.h>

#define B_ 2
#define S_ 2048
#define E_ 2048
#define H_ 16
#define D_ 128
#define M_ (B_*S_)
#define NQKV_ (3*E_)

typedef __attribute__((ext_vector_type(8))) short bf16x8;
typedef __attribute__((ext_vector_type(4))) float f32x4;
typedef __attribute__((ext_vector_type(4))) unsigned short u16x4;

__device__ __forceinline__ unsigned short f2bf(float f) {
  union { float f; unsigned u; } v; v.f = f;
  unsigned r = v.u + 0x7fffu + ((v.u >> 16) & 1u);
  return (unsigned short)(r >> 16);
}
__device__ __forceinline__ float bf2f(unsigned short h) {
  union { unsigned u; float f; } v; v.u = ((unsigned)h) << 16;
  return v.f;
}

__device__ __forceinline__ void gload_lds16(const void* g, void* l) {
  __builtin_amdgcn_global_load_lds(
      (const __attribute__((address_space(1))) unsigned*)g,
      (__attribute__((address_space(3))) unsigned*)l, 16, 0, 0);
}

// ---------------------------------------------------------------- prep
__global__ __launch_bounds__(256) void prep_kernel(
    const float* __restrict__ hs,
    const float* __restrict__ Wq, const float* __restrict__ Wk, const float* __restrict__ Wv,
    const float* __restrict__ Wo,
    const float* __restrict__ bq, const float* __restrict__ bk, const float* __restrict__ bv,
    unsigned short* __restrict__ hsb, unsigned short* __restrict__ Wqkv,
    unsigned short* __restrict__ Wob, float* __restrict__ biasqkv,
    float* __restrict__ cosT, float* __restrict__ sinT)
{
  const int seg = blockIdx.y;
  const int t0 = blockIdx.x * 256 + threadIdx.x;
  const int stride = gridDim.x * 256;
  if (seg == 0) {
    const int n = (M_*E_)/4;
    for (int i = t0; i < n; i += stride) {
      f32x4 v = ((const f32x4*)hs)[i];
      u16x4 o; o[0]=f2bf(v[0]); o[1]=f2bf(v[1]); o[2]=f2bf(v[2]); o[3]=f2bf(v[3]);
      ((u16x4*)hsb)[i] = o;
    }
  } else if (seg == 1) {
    const int n = (3*E_*E_)/4;
    for (int i = t0; i < n; i += stride) {
      int e4 = i << 2;
      int r = e4 >> 11;
      int k = e4 & 2047;
      const float* src = (r < E_) ? (Wq + ((size_t)r << 11) + k)
                       : (r < 2*E_) ? (Wk + ((size_t)(r - E_) << 11) + k)
                       : (Wv + ((size_t)(r - 2*E_) << 11) + k);
      f32x4 v = *(const f32x4*)src;
      u16x4 o; o[0]=f2bf(v[0]); o[1]=f2bf(v[1]); o[2]=f2bf(v[2]); o[3]=f2bf(v[3]);
      ((u16x4*)Wqkv)[i] = o;
    }
  } else if (seg == 2) {
    const int n = (E_*E_)/4;
    for (int i = t0; i < n; i += stride) {
      f32x4 v = ((const f32x4*)Wo)[i];
      u16x4 o; o[0]=f2bf(v[0]); o[1]=f2bf(v[1]); o[2]=f2bf(v[2]); o[3]=f2bf(v[3]);
      ((u16x4*)Wob)[i] = o;
    }
  } else if (seg == 3) {
    for (int i = t0; i < NQKV_; i += stride)
      biasqkv[i] = (i < E_) ? bq[i] : (i < 2*E_) ? bk[i - E_] : bv[i - 2*E_];
  } else {
    for (int i = t0; i < S_*64; i += stride) {
      int j = i & 63, s = i >> 6;
      float inv = exp2f(-(float)j * (13.287712379549449f / 64.0f)); // 10000^(-j/64)
      float ang = (float)s * inv;
      cosT[i] = cosf(ang);
      sinT[i] = sinf(ang);
    }
  }
}

// ------------------------------------------------- GEMM  C = A * B^T + bias
// A [M][K] bf16, Bm [N][K] bf16, 128x128 tile, BK=64, 4 waves, swizzled LDS.
template<int OUT_F32>
__global__ __launch_bounds__(256) void gemm_bt(
    const unsigned short* __restrict__ A,
    const unsigned short* __restrict__ Bm,
    const float* __restrict__ bias,
    void* __restrict__ Cv,
    int M, int N, int K)
{
  __shared__ unsigned short lA[128*64];
  __shared__ unsigned short lB[128*64];
  const int tid = threadIdx.x;
  const int lane = tid & 63;
  const int w = tid >> 6;
  const int wr = w >> 1, wc = w & 1;
  const int ntile = N >> 7;
  const int tm = blockIdx.x / ntile, tn = blockIdx.x % ntile;
  const int l15 = lane & 15, l4 = lane >> 4;

  f32x4 acc[4][4] = {};

  for (int kt = 0; kt < K; kt += 64) {
    #pragma unroll
    for (int i = 0; i < 4; ++i) {
      int cc = i*256 + tid;
      int row = cc >> 3, col = cc & 7;
      int scol = col ^ (row & 7);
      gload_lds16(A + (size_t)(tm*128 + row)*K + kt + scol*8, (char*)lA + cc*16);
    }
    #pragma unroll
    for (int i = 0; i < 4; ++i) {
      int cc = i*256 + tid;
      int row = cc >> 3, col = cc & 7;
      int scol = col ^ (row & 7);
      gload_lds16(Bm + (size_t)(tn*128 + row)*K + kt + scol*8, (char*)lB + cc*16);
    }
    asm volatile("s_waitcnt vmcnt(0)" ::: "memory");
    __syncthreads();

    #pragma unroll
    for (int ks = 0; ks < 2; ++ks) {
      bf16x8 af[4], bfr[4];
      #pragma unroll
      for (int mt = 0; mt < 4; ++mt) {
        int row = wr*64 + mt*16 + l15;
        int ch = (ks*4 + l4) ^ (row & 7);
        af[mt] = *(const bf16x8*)(lA + row*64 + ch*8);
      }
      #pragma unroll
      for (int nt = 0; nt < 4; ++nt) {
        int row = wc*64 + nt*16 + l15;
        int ch = (ks*4 + l4) ^ (row & 7);
        bfr[nt] = *(const bf16x8*)(lB + row*64 + ch*8);
      }
      #pragma unroll
      for (int mt = 0; mt < 4; ++mt)
        #pragma unroll
        for (int nt = 0; nt < 4; ++nt)
          acc[mt][nt] = __builtin_amdgcn_mfma_f32_16x16x32_bf16(af[mt], bfr[nt], acc[mt][nt], 0, 0, 0);
    }
    __syncthreads();
  }

  #pragma unroll
  for (int mt = 0; mt < 4; ++mt) {
    #pragma unroll
    for (int nt = 0; nt < 4; ++nt) {
      int colg = tn*128 + wc*64 + nt*16 + l15;
      float bvv = bias[colg];
      #pragma unroll
      for (int r = 0; r < 4; ++r) {
        int rowg = tm*128 + wr*64 + mt*16 + l4*4 + r;
        float v = acc[mt][nt][r] + bvv;
        if (OUT_F32) ((float*)Cv)[(size_t)rowg*N + colg] = v;
        else ((unsigned short*)Cv)[(size_t)rowg*N + colg] = f2bf(v);
      }
    }
  }
}

// ---------------------------------------------------------------- RoPE (in-place on qkv)
__global__ __launch_bounds__(256) void rope_kernel(
    unsigned short* __restrict__ qkv, const float* __restrict__ cosT, const float* __restrict__ sinT)
{
  int t = blockIdx.x*256 + threadIdx.x;            // M_*H_*64 threads
  int i  = t & 63;
  int h  = (t >> 6) & 15;
  int m  = t >> 10;
  int s  = m & (S_-1);
  float c = cosT[s*64 + i], sn = sinT[s*64 + i];
  const float scale = 0.08838834764831845f;        // 1/sqrt(128)
  size_t base = (size_t)m*NQKV_ + h*128;
  float q1 = bf2f(qkv[base+i]), q2 = bf2f(qkv[base+64+i]);
  qkv[base+i]    = f2bf((q1*c - q2*sn)*scale);
  qkv[base+64+i] = f2bf((q2*c + q1*sn)*scale);
  size_t kb = base + E_;
  float k1 = bf2f(qkv[kb+i]), k2 = bf2f(qkv[kb+64+i]);
  qkv[kb+i]    = f2bf(k1*c - k2*sn);
  qkv[kb+64+i] = f2bf(k2*c + k1*sn);
}

// ---------------------------------------------------------------- V transpose -> [B,H,D,S]
__global__ __launch_bounds__(256) void transv_kernel(
    const unsigned short* __restrict__ qkv, unsigned short* __restrict__ Vt)
{
  __shared__ unsigned short t[32][33];
  int bid = blockIdx.x;
  int st = bid & 63;
  int dt = (bid >> 6) & 3;
  int bh = bid >> 8;
  int b = bh >> 4, h = bh & 15;
  int tx = threadIdx.x & 31, ty = threadIdx.x >> 5;
  #pragma unroll
  for (int j = 0; j < 4; ++j) {
    int r = ty + j*8;
    t[r][tx] = qkv[(size_t)(b*S_ + st*32 + r)*NQKV_ + 2*E_ + h*128 + dt*32 + tx];
  }
  __syncthreads();
  #pragma unroll
  for (int j = 0; j < 4; ++j) {
    int r = ty + j*8;
    Vt[((size_t)bh*D_ + dt*32 + r)*S_ + st*32 + tx] = t[tx][r];
  }
}

// ---------------------------------------------------------------- flash attention
__global__ __launch_bounds__(256) void attn_kernel(
    const unsigned short* __restrict__ qkv, const unsigned short* __restrict__ Vt,
    unsigned short* __restrict__ Ao)
{
  __shared__ unsigned short lK[64*128];  // [64 keys][16 chunks] swizzled
  __shared__ unsigned short lV[128*64];  // [128 d][8 chunks] swizzled (V^T)
  __shared__ float lP[4*16*64];          // per-wave P, swizzled
  const int bid = blockIdx.x;
  const int qt = bid & 31;
  const int bh = bid >> 5;
  const int b = bh >> 4, h = bh & 15;
  const int tid = threadIdx.x, lane = tid & 63, w = tid >> 6;
  const int l15 = lane & 15, l4 = lane >> 4;

  const int qrow = qt*64 + w*16 + l15;
  const unsigned short* qp = qkv + (size_t)(b*S_ + qrow)*NQKV_ + h*128 + l4*8;
  bf16x8 qf[4];
  #pragma unroll
  for (int f = 0; f < 4; ++f) qf[f] = *(const bf16x8*)(qp + f*32);

  f32x4 O[8];
  #pragma unroll
  for (int i = 0; i < 8; ++i) O[i] = (f32x4){0.f,0.f,0.f,0.f};
  float mrow[4] = {-1e30f,-1e30f,-1e30f,-1e30f};
  float lrow[4] = {0.f,0.f,0.f,0.f};

  float* myP = lP + w*(16*64);
  const size_t kbase = (size_t)b*S_*NQKV_ + E_ + (size_t)h*128;
  const size_t vbase = (size_t)bh*D_*S_;

  for (int kt = 0; kt < S_; kt += 64) {
    #pragma unroll
    for (int i = 0; i < 4; ++i) {
      int cc = i*256 + tid;
      int row = cc >> 4, col = cc & 15;
      int scol = col ^ (row & 7);
      gload_lds16(qkv + kbase + (size_t)(kt + row)*NQKV_ + scol*8, (char*)lK + cc*16);
    }
    #pragma unroll
    for (int i = 0; i < 4; ++i) {
      int cc = i*256 + tid;
      int row = cc >> 3, col = cc & 7;
      int scol = col ^ ((row & 7) ^ ((row >> 3) & 7));
      gload_lds16(Vt + vbase + (size_t)row*S_ + kt + scol*8, (char*)lV + cc*16);
    }
    asm volatile("s_waitcnt vmcnt(0)" ::: "memory");
    __syncthreads();

    // S = Q K^T (Q pre-scaled by 1/sqrt(D))
    f32x4 sfr[4];
    #pragma unroll
    for (int nf = 0; nf < 4; ++nf) {
      f32x4 s = (f32x4){0.f,0.f,0.f,0.f};
      #pragma unroll
      for (int ks = 0; ks < 4; ++ks) {
        int row = nf*16 + l15;
        int ch = (ks*4 + l4) ^ (row & 7);
        bf16x8 kf = *(const bf16x8*)(lK + row*128 + ch*8);
        s = __builtin_amdgcn_mfma_f32_16x16x32_bf16(qf[ks], kf, s, 0, 0, 0);
      }
      sfr[nf] = s;
    }

    // online softmax (rows live on lanes sharing l>>4; reduce over l&15)
    #pragma unroll
    for (int r = 0; r < 4; ++r) {
      float vmax = fmaxf(fmaxf(sfr[0][r], sfr[1][r]), fmaxf(sfr[2][r], sfr[3][r]));
      #pragma unroll
      for (int msk = 1; msk <= 8; msk <<= 1) vmax = fmaxf(vmax, __shfl_xor(vmax, msk, 64));
      float mn = fmaxf(mrow[r], vmax);
      float alpha = __expf(mrow[r] - mn);
      mrow[r] = mn;
      float ps = 0.f;
      #pragma unroll
      for (int nf = 0; nf < 4; ++nf) {
        float pv = __expf(sfr[nf][r] - mn);
        sfr[nf][r] = pv;
        ps += pv;
      }
      #pragma unroll
      for (int msk = 1; msk <= 8; msk <<= 1) ps += __shfl_xor(ps, msk, 64);
      lrow[r] = lrow[r]*alpha + ps;
      #pragma unroll
      for (int df = 0; df < 8; ++df) O[df][r] *= alpha;
    }

    // P -> wave-private LDS (f32, swizzled, conflict-free)
    #pragma unroll
    for (int nf = 0; nf < 4; ++nf) {
      #pragma unroll
      for (int r = 0; r < 4; ++r) {
        int q = l4*4 + r;
        int k = nf*16 + l15;
        myP[q*64 + (k ^ ((q & 7) << 2))] = sfr[nf][r];
      }
    }
    asm volatile("s_waitcnt lgkmcnt(0)" ::: "memory");

    // O += P V
    #pragma unroll
    for (int ks2 = 0; ks2 < 2; ++ks2) {
      int q = l15;
      int k0 = ks2*32 + l4*8;
      int sw = (q & 7) << 2;
      f32x4 p0 = *(const f32x4*)(myP + q*64 + (k0 ^ sw));
      f32x4 p1 = *(const f32x4*)(myP + q*64 + ((k0 + 4) ^ sw));
      bf16x8 pf;
      #pragma unroll
      for (int j = 0; j < 4; ++j) { pf[j] = (short)f2bf(p0[j]); pf[j+4] = (short)f2bf(p1[j]); }
      #pragma unroll
      for (int df = 0; df < 8; ++df) {
        int row = df*16 + l15;
        int ch = (ks2*4 + l4) ^ ((row & 7) ^ ((row >> 3) & 7));
        bf16x8 vf = *(const bf16x8*)(lV + row*64 + ch*8);
        O[df] = __builtin_amdgcn_mfma_f32_16x16x32_bf16(pf, vf, O[df], 0, 0, 0);
      }
    }
    __syncthreads();
  }

  float inv[4];
  #pragma unroll
  for (int r = 0; r < 4; ++r) inv[r] = 1.0f / lrow[r];
  #pragma unroll
  for (int df = 0; df < 8; ++df) {
    int colg = h*128 + df*16 + l15;
    #pragma unroll
    for (int r = 0; r < 4; ++r) {
      int rowg = qt*64 + w*16 + l4*4 + r;
      Ao[(size_t)(b*S_ + rowg)*E_ + colg] = f2bf(O[df][r] * inv[r]);
    }
  }
}

// ----------------------------------------------------------------
extern "C" void kernel_launch(void* const* d_in, const int* in_sizes, int n_in,
                              void* d_out, int out_size, void* d_ws, size_t ws_size,
                              hipStream_t stream) {
  const float* hs = (const float*)d_in[0];
  const float* Wq = (const float*)d_in[1];
  const float* bq = (const float*)d_in[2];
  const float* Wk = (const float*)d_in[3];
  const float* bk = (const float*)d_in[4];
  const float* Wv = (const float*)d_in[5];
  const float* bv = (const float*)d_in[6];
  const float* Wo = (const float*)d_in[7];
  const float* bo = (const float*)d_in[8];
  float* out = (float*)d_out;

  char* p = (char*)d_ws;
  auto alloc = [&](size_t bytes) { char* r = p; p += (bytes + 255) & ~(size_t)255; return r; };
  unsigned short* hsb  = (unsigned short*)alloc((size_t)M_*E_*2);
  unsigned short* Wqkv = (unsigned short*)alloc((size_t)NQKV_*E_*2);
  unsigned short* Wob  = (unsigned short*)alloc((size_t)E_*E_*2);
  unsigned short* qkv  = (unsigned short*)alloc((size_t)M_*NQKV_*2);
  unsigned short* Vt   = (unsigned short*)alloc((size_t)B_*H_*D_*S_*2);
  unsigned short* Ao   = (unsigned short*)alloc((size_t)M_*E_*2);
  float* biasqkv = (float*)alloc((size_t)NQKV_*4);
  float* cosT = (float*)alloc((size_t)S_*64*4);
  float* sinT = (float*)alloc((size_t)S_*64*4);

  prep_kernel<<<dim3(2048, 5), 256, 0, stream>>>(hs, Wq, Wk, Wv, Wo, bq, bk, bv,
      hsb, Wqkv, Wob, biasqkv, cosT, sinT);
  gemm_bt<0><<<dim3((M_/128)*(NQKV_/128)), 256, 0, stream>>>(hsb, Wqkv, biasqkv, qkv, M_, NQKV_, E_);
  rope_kernel<<<dim3((M_*H_*64)/256), 256, 0, stream>>>(qkv, cosT, sinT);
  transv_kernel<<<dim3(B_*H_*(D_/32)*(S_/32)), 256, 0, stream>>>(qkv, Vt);
  attn_kernel<<<dim3(B_*H_*(S_/64)), 256, 0, stream>>>(qkv, Vt, Ao);
  gemm_bt<1><<<dim3((M_/128)*(E_/128)), 256, 0, stream>>>(Ao, Wob, bo, out, M_, E_, E_);
}

// Round 2
// 323.422 us; speedup vs baseline: 1.2081x; 1.2081x over previous
//
#include <hip/hip_runtime.h>
#include <hip/hip_bf16.h>

#define B_ 2
#define S_ 2048
#define E_ 2048
#define H_ 16
#define D_ 128
#define M_ (B_*S_)
#define NQKV_ (3*E_)

typedef __attribute__((ext_vector_type(8))) short bf16x8;
typedef __attribute__((ext_vector_type(4))) float f32x4;
typedef __attribute__((ext_vector_type(4))) unsigned short u16x4;
typedef __attribute__((ext_vector_type(2))) unsigned u32x2;

__device__ __forceinline__ unsigned short f2bf(float f) {
  union { float f; unsigned u; } v; v.f = f;
  unsigned r = v.u + 0x7fffu + ((v.u >> 16) & 1u);
  return (unsigned short)(r >> 16);
}
__device__ __forceinline__ float bf2f(unsigned short h) {
  union { unsigned u; float f; } v; v.u = ((unsigned)h) << 16;
  return v.f;
}

__device__ __forceinline__ void gload_lds16(const void* g, void* l) {
  __builtin_amdgcn_global_load_lds(
      (const __attribute__((address_space(1))) unsigned*)g,
      (__attribute__((address_space(3))) unsigned*)l, 16, 0, 0);
}

// ---------------------------------------------------------------- prep
__global__ __launch_bounds__(256) void prep_kernel(
    const float* __restrict__ hs,
    const float* __restrict__ Wq, const float* __restrict__ Wk, const float* __restrict__ Wv,
    const float* __restrict__ Wo,
    const float* __restrict__ bq, const float* __restrict__ bk, const float* __restrict__ bv,
    unsigned short* __restrict__ hsb, unsigned short* __restrict__ Wqkv,
    unsigned short* __restrict__ Wob, float* __restrict__ biasqkv,
    float* __restrict__ cosT, float* __restrict__ sinT)
{
  const int seg = blockIdx.y;
  const int t0 = blockIdx.x * 256 + threadIdx.x;
  const int stride = gridDim.x * 256;
  if (seg == 0) {
    const int n = (M_*E_)/4;
    for (int i = t0; i < n; i += stride) {
      f32x4 v = ((const f32x4*)hs)[i];
      u16x4 o; o[0]=f2bf(v[0]); o[1]=f2bf(v[1]); o[2]=f2bf(v[2]); o[3]=f2bf(v[3]);
      ((u16x4*)hsb)[i] = o;
    }
  } else if (seg == 1) {
    const int n = (3*E_*E_)/4;
    for (int i = t0; i < n; i += stride) {
      int e4 = i << 2;
      int r = e4 >> 11;
      int k = e4 & 2047;
      const float* src = (r < E_) ? (Wq + ((size_t)r << 11) + k)
                       : (r < 2*E_) ? (Wk + ((size_t)(r - E_) << 11) + k)
                       : (Wv + ((size_t)(r - 2*E_) << 11) + k);
      f32x4 v = *(const f32x4*)src;
      u16x4 o; o[0]=f2bf(v[0]); o[1]=f2bf(v[1]); o[2]=f2bf(v[2]); o[3]=f2bf(v[3]);
      ((u16x4*)Wqkv)[i] = o;
    }
  } else if (seg == 2) {
    const int n = (E_*E_)/4;
    for (int i = t0; i < n; i += stride) {
      f32x4 v = ((const f32x4*)Wo)[i];
      u16x4 o; o[0]=f2bf(v[0]); o[1]=f2bf(v[1]); o[2]=f2bf(v[2]); o[3]=f2bf(v[3]);
      ((u16x4*)Wob)[i] = o;
    }
  } else if (seg == 3) {
    for (int i = t0; i < NQKV_; i += stride)
      biasqkv[i] = (i < E_) ? bq[i] : (i < 2*E_) ? bk[i - E_] : bv[i - 2*E_];
  } else {
    for (int i = t0; i < S_*64; i += stride) {
      int j = i & 63, s = i >> 6;
      float inv = exp2f(-(float)j * (13.287712379549449f / 64.0f)); // 10000^(-j/64)
      float ang = (float)s * inv;
      cosT[i] = cosf(ang);
      sinT[i] = sinf(ang);
    }
  }
}

// ------------------------------------------------- GEMM  C = A * B^T + bias
template<int OUT_F32>
__global__ __launch_bounds__(256) void gemm_bt(
    const unsigned short* __restrict__ A,
    const unsigned short* __restrict__ Bm,
    const float* __restrict__ bias,
    void* __restrict__ Cv,
    int M, int N, int K)
{
  __shared__ unsigned short lA[128*64];
  __shared__ unsigned short lB[128*64];
  const int tid = threadIdx.x;
  const int lane = tid & 63;
  const int w = tid >> 6;
  const int wr = w >> 1, wc = w & 1;
  const int ntile = N >> 7;
  const int tm = blockIdx.x / ntile, tn = blockIdx.x % ntile;
  const int l15 = lane & 15, l4 = lane >> 4;

  f32x4 acc[4][4] = {};

  for (int kt = 0; kt < K; kt += 64) {
    #pragma unroll
    for (int i = 0; i < 4; ++i) {
      int cc = i*256 + tid;
      int row = cc >> 3, col = cc & 7;
      int scol = col ^ (row & 7);
      gload_lds16(A + (size_t)(tm*128 + row)*K + kt + scol*8, (char*)lA + cc*16);
    }
    #pragma unroll
    for (int i = 0; i < 4; ++i) {
      int cc = i*256 + tid;
      int row = cc >> 3, col = cc & 7;
      int scol = col ^ (row & 7);
      gload_lds16(Bm + (size_t)(tn*128 + row)*K + kt + scol*8, (char*)lB + cc*16);
    }
    asm volatile("s_waitcnt vmcnt(0)" ::: "memory");
    __syncthreads();

    #pragma unroll
    for (int ks = 0; ks < 2; ++ks) {
      bf16x8 af[4], bfr[4];
      #pragma unroll
      for (int mt = 0; mt < 4; ++mt) {
        int row = wr*64 + mt*16 + l15;
        int ch = (ks*4 + l4) ^ (row & 7);
        af[mt] = *(const bf16x8*)(lA + row*64 + ch*8);
      }
      #pragma unroll
      for (int nt = 0; nt < 4; ++nt) {
        int row = wc*64 + nt*16 + l15;
        int ch = (ks*4 + l4) ^ (row & 7);
        bfr[nt] = *(const bf16x8*)(lB + row*64 + ch*8);
      }
      #pragma unroll
      for (int mt = 0; mt < 4; ++mt)
        #pragma unroll
        for (int nt = 0; nt < 4; ++nt)
          acc[mt][nt] = __builtin_amdgcn_mfma_f32_16x16x32_bf16(af[mt], bfr[nt], acc[mt][nt], 0, 0, 0);
    }
    __syncthreads();
  }

  #pragma unroll
  for (int mt = 0; mt < 4; ++mt) {
    #pragma unroll
    for (int nt = 0; nt < 4; ++nt) {
      int colg = tn*128 + wc*64 + nt*16 + l15;
      float bvv = bias[colg];
      #pragma unroll
      for (int r = 0; r < 4; ++r) {
        int rowg = tm*128 + wr*64 + mt*16 + l4*4 + r;
        float v = acc[mt][nt][r] + bvv;
        if (OUT_F32) ((float*)Cv)[(size_t)rowg*N + colg] = v;
        else ((unsigned short*)Cv)[(size_t)rowg*N + colg] = f2bf(v);
      }
    }
  }
}

// ---------------------------------------------------------------- RoPE (in-place on qkv)
// q additionally scaled by log2(e)/sqrt(D) so attention works in exp2 domain.
__global__ __launch_bounds__(256) void rope_kernel(
    unsigned short* __restrict__ qkv, const float* __restrict__ cosT, const float* __restrict__ sinT)
{
  int t = blockIdx.x*256 + threadIdx.x;            // M_*H_*64 threads
  int i  = t & 63;
  int h  = (t >> 6) & 15;
  int m  = t >> 10;
  int s  = m & (S_-1);
  float c = cosT[s*64 + i], sn = sinT[s*64 + i];
  const float scale = 0.08838834764831845f * 1.4426950408889634f; // log2e/sqrt(128)
  size_t base = (size_t)m*NQKV_ + h*128;
  float q1 = bf2f(qkv[base+i]), q2 = bf2f(qkv[base+64+i]);
  qkv[base+i]    = f2bf((q1*c - q2*sn)*scale);
  qkv[base+64+i] = f2bf((q2*c + q1*sn)*scale);
  size_t kb = base + E_;
  float k1 = bf2f(qkv[kb+i]), k2 = bf2f(qkv[kb+64+i]);
  qkv[kb+i]    = f2bf(k1*c - k2*sn);
  qkv[kb+64+i] = f2bf(k2*c + k1*sn);
}

// ---------------------------------------------------------------- V transpose -> [B,H,D,S]
__global__ __launch_bounds__(256) void transv_kernel(
    const unsigned short* __restrict__ qkv, unsigned short* __restrict__ Vt)
{
  __shared__ unsigned short t[32][33];
  int bid = blockIdx.x;
  int st = bid & 63;
  int dt = (bid >> 6) & 3;
  int bh = bid >> 8;
  int b = bh >> 4, h = bh & 15;
  int tx = threadIdx.x & 31, ty = threadIdx.x >> 5;
  #pragma unroll
  for (int j = 0; j < 4; ++j) {
    int r = ty + j*8;
    t[r][tx] = qkv[(size_t)(b*S_ + st*32 + r)*NQKV_ + 2*E_ + h*128 + dt*32 + tx];
  }
  __syncthreads();
  #pragma unroll
  for (int j = 0; j < 4; ++j) {
    int r = ty + j*8;
    Vt[((size_t)bh*D_ + dt*32 + r)*S_ + st*32 + tx] = t[tx][r];
  }
}

// ---------------------------------------------------------------- flash attention
// Swapped QK^T (S^T = K Q^T): per-lane q = lane&15, keys in registers ->
// in-lane softmax + 2 shuffles. P: bf16 in wave-private LDS via ds_write_b64,
// swizzle k ^= (q&7)<<3 (conflict-free write b64 + read b128).
__global__ __launch_bounds__(256, 4) void attn_kernel(
    const unsigned short* __restrict__ qkv, const unsigned short* __restrict__ Vt,
    unsigned short* __restrict__ Ao)
{
  __shared__ unsigned short lK[64*128];                 // 16 KB
  __shared__ unsigned short lV[128*64];                 // 16 KB
  __shared__ __align__(16) unsigned short lP[4*16*64];  // 8 KB (bf16 P per wave)
  const int bid = blockIdx.x;
  const int qt = bid & 31;
  const int bh = bid >> 5;
  const int b = bh >> 4, h = bh & 15;
  const int tid = threadIdx.x, lane = tid & 63, w = tid >> 6;
  const int l15 = lane & 15, l4 = lane >> 4;

  const int qrow = qt*64 + w*16 + l15;
  const unsigned short* qp = qkv + (size_t)(b*S_ + qrow)*NQKV_ + h*128 + l4*8;
  bf16x8 qf[4];
  #pragma unroll
  for (int f = 0; f < 4; ++f) qf[f] = *(const bf16x8*)(qp + f*32);

  f32x4 O[8];
  #pragma unroll
  for (int i = 0; i < 8; ++i) O[i] = (f32x4){0.f,0.f,0.f,0.f};
  float m = -1e30f, lsum = 0.f;

  unsigned short* myP = lP + w*(16*64);
  const int ksw = (l15 & 7) << 3;
  const size_t kbase = (size_t)b*S_*NQKV_ + E_ + (size_t)h*128;
  const size_t vbase = (size_t)bh*D_*S_;

  for (int kt = 0; kt < S_; kt += 64) {
    #pragma unroll
    for (int i = 0; i < 4; ++i) {
      int cc = i*256 + tid;
      int row = cc >> 4, col = cc & 15;
      int scol = col ^ (row & 7);
      gload_lds16(qkv + kbase + (size_t)(kt + row)*NQKV_ + scol*8, (char*)lK + cc*16);
    }
    #pragma unroll
    for (int i = 0; i < 4; ++i) {
      int cc = i*256 + tid;
      int row = cc >> 3, col = cc & 7;
      int scol = col ^ ((row & 7) ^ ((row >> 3) & 7));
      gload_lds16(Vt + vbase + (size_t)row*S_ + kt + scol*8, (char*)lV + cc*16);
    }
    asm volatile("s_waitcnt vmcnt(0)" ::: "memory");
    __syncthreads();

    // S^T = K Q^T : sfr[nf][r] = S[key = kt + nf*16 + l4*4 + r][q = l15]
    f32x4 sfr[4];
    #pragma unroll
    for (int nf = 0; nf < 4; ++nf) {
      f32x4 s = (f32x4){0.f,0.f,0.f,0.f};
      #pragma unroll
      for (int ks = 0; ks < 4; ++ks) {
        int row = nf*16 + l15;
        int ch = (ks*4 + l4) ^ (row & 7);
        bf16x8 kf = *(const bf16x8*)(lK + row*128 + ch*8);
        s = __builtin_amdgcn_mfma_f32_16x16x32_bf16(kf, qf[ks], s, 0, 0, 0);
      }
      sfr[nf] = s;
    }

    // in-lane row max (16 vals) + reduce over l4 groups (2 shuffles)
    float vmax = -1e30f;
    #pragma unroll
    for (int nf = 0; nf < 4; ++nf)
      #pragma unroll
      for (int r = 0; r < 4; ++r) vmax = fmaxf(vmax, sfr[nf][r]);
    vmax = fmaxf(vmax, __shfl_xor(vmax, 16, 64));
    vmax = fmaxf(vmax, __shfl_xor(vmax, 32, 64));

    // defer-max: rescale only when row max grows by > 8 (base-2 domain)
    if (__any(vmax > m + 8.0f)) {
      float mn = fmaxf(m, vmax);
      float al = __builtin_amdgcn_exp2f(m - mn);
      m = mn;
      lsum *= al;
      #pragma unroll
      for (int r = 0; r < 4; ++r) {
        float ar = __shfl(al, (lane & 48) + l4*4 + r, 64);
        #pragma unroll
        for (int df = 0; df < 8; ++df) O[df][r] *= ar;
      }
    }

    float ps = 0.f;
    #pragma unroll
    for (int nf = 0; nf < 4; ++nf) {
      #pragma unroll
      for (int r = 0; r < 4; ++r) {
        float p = __builtin_amdgcn_exp2f(sfr[nf][r] - m);
        sfr[nf][r] = p;
        ps += p;
      }
    }
    ps += __shfl_xor(ps, 16, 64);
    ps += __shfl_xor(ps, 32, 64);
    lsum += ps;

    // pack P -> bf16 LDS (wave-private), 4x ds_write_b64, conflict-free swizzle
    #pragma unroll
    for (int nf = 0; nf < 4; ++nf) {
      unsigned lo = (unsigned)f2bf(sfr[nf][0]) | ((unsigned)f2bf(sfr[nf][1]) << 16);
      unsigned hi = (unsigned)f2bf(sfr[nf][2]) | ((unsigned)f2bf(sfr[nf][3]) << 16);
      int k0 = (nf*16 + l4*4) ^ ksw;
      u32x2 val; val[0] = lo; val[1] = hi;
      *(u32x2*)(myP + l15*64 + k0) = val;
    }
    asm volatile("s_waitcnt lgkmcnt(0)" ::: "memory");

    // O += P V
    #pragma unroll
    for (int ks2 = 0; ks2 < 2; ++ks2) {
      int kk = (ks2*32 + l4*8) ^ ksw;
      bf16x8 pf = *(const bf16x8*)(myP + l15*64 + kk);
      #pragma unroll
      for (int df = 0; df < 8; ++df) {
        int row = df*16 + l15;
        int ch = (ks2*4 + l4) ^ ((row & 7) ^ ((row >> 3) & 7));
        bf16x8 vf = *(const bf16x8*)(lV + row*64 + ch*8);
        O[df] = __builtin_amdgcn_mfma_f32_16x16x32_bf16(pf, vf, O[df], 0, 0, 0);
      }
    }
    __syncthreads();
  }

  float linv = 1.0f / lsum;
  float inv[4];
  #pragma unroll
  for (int r = 0; r < 4; ++r) inv[r] = __shfl(linv, (lane & 48) + l4*4 + r, 64);
  #pragma unroll
  for (int df = 0; df < 8; ++df) {
    int colg = h*128 + df*16 + l15;
    #pragma unroll
    for (int r = 0; r < 4; ++r) {
      int rowg = qt*64 + w*16 + l4*4 + r;
      Ao[(size_t)(b*S_ + rowg)*E_ + colg] = f2bf(O[df][r] * inv[r]);
    }
  }
}

// ----------------------------------------------------------------
extern "C" void kernel_launch(void* const* d_in, const int* in_sizes, int n_in,
                              void* d_out, int out_size, void* d_ws, size_t ws_size,
                              hipStream_t stream) {
  const float* hs = (const float*)d_in[0];
  const float* Wq = (const float*)d_in[1];
  const float* bq = (const float*)d_in[2];
  const float* Wk = (const float*)d_in[3];
  const float* bk = (const float*)d_in[4];
  const float* Wv = (const float*)d_in[5];
  const float* bv = (const float*)d_in[6];
  const float* Wo = (const float*)d_in[7];
  const float* bo = (const float*)d_in[8];
  float* out = (float*)d_out;

  char* p = (char*)d_ws;
  auto alloc = [&](size_t bytes) { char* r = p; p += (bytes + 255) & ~(size_t)255; return r; };
  unsigned short* hsb  = (unsigned short*)alloc((size_t)M_*E_*2);
  unsigned short* Wqkv = (unsigned short*)alloc((size_t)NQKV_*E_*2);
  unsigned short* Wob  = (unsigned short*)alloc((size_t)E_*E_*2);
  unsigned short* qkv  = (unsigned short*)alloc((size_t)M_*NQKV_*2);
  unsigned short* Vt   = (unsigned short*)alloc((size_t)B_*H_*D_*S_*2);
  unsigned short* Ao   = (unsigned short*)alloc((size_t)M_*E_*2);
  float* biasqkv = (float*)alloc((size_t)NQKV_*4);
  float* cosT = (float*)alloc((size_t)S_*64*4);
  float* sinT = (float*)alloc((size_t)S_*64*4);

  prep_kernel<<<dim3(2048, 5), 256, 0, stream>>>(hs, Wq, Wk, Wv, Wo, bq, bk, bv,
      hsb, Wqkv, Wob, biasqkv, cosT, sinT);
  gemm_bt<0><<<dim3((M_/128)*(NQKV_/128)), 256, 0, stream>>>(hsb, Wqkv, biasqkv, qkv, M_, NQKV_, E_);
  rope_kernel<<<dim3((M_*H_*64)/256), 256, 0, stream>>>(qkv, cosT, sinT);
  transv_kernel<<<dim3(B_*H_*(D_/32)*(S_/32)), 256, 0, stream>>>(qkv, Vt);
  attn_kernel<<<dim3(B_*H_*(S_/64)), 256, 0, stream>>>(qkv, Vt, Ao);
  gemm_bt<1><<<dim3((M_/128)*(E_/128)), 256, 0, stream>>>(Ao, Wob, bo, out, M_, E_, E_);
}